// Round 1
// baseline (107.326 us; speedup 1.0000x reference)
//
#include <hip/hip_runtime.h>
#include <math.h>

#define CCH   192
#define RCH   48
#define NB    16
#define HW    9216    // 96*96
#define BCTOT (NB*CCH) // 3072

// ---------------------------------------------------------------------------
// Kernel 1: per-(b,c) plane -> avg, max, 3x3 pooled means
// One block per (b,c). Each pooled 32x32 block = 256 float4 = exactly blockDim.
// ---------------------------------------------------------------------------
__global__ __launch_bounds__(256) void k_stats(const float* __restrict__ x,
                                               float* __restrict__ avg,
                                               float* __restrict__ mx,
                                               float* __restrict__ pooled)
{
    int bc = blockIdx.x;
    const float4* p4 = (const float4*)(x + (size_t)bc * HW);
    int t = threadIdx.x;
    float ps[9];
    float m = -INFINITY;
#pragma unroll
    for (int k = 0; k < 9; ++k) {
        int kr = k / 3, kc = k % 3;
        int row = kr * 32 + (t >> 3);
        int wq  = kc * 8  + (t & 7);
        float4 v = p4[row * 24 + wq];
        ps[k] = v.x + v.y + v.z + v.w;
        m = fmaxf(m, fmaxf(fmaxf(v.x, v.y), fmaxf(v.z, v.w)));
    }
    // wave (64-lane) reduction
#pragma unroll
    for (int off = 32; off > 0; off >>= 1) {
#pragma unroll
        for (int k = 0; k < 9; ++k) ps[k] += __shfl_down(ps[k], off);
        m = fmaxf(m, __shfl_down(m, off));
    }
    __shared__ float red[4][10];
    int wid = t >> 6, lane = t & 63;
    if (lane == 0) {
#pragma unroll
        for (int k = 0; k < 9; ++k) red[wid][k] = ps[k];
        red[wid][9] = m;
    }
    __syncthreads();
    if (t == 0) {
        float tot = 0.f;
#pragma unroll
        for (int k = 0; k < 9; ++k) {
            float pk = red[0][k] + red[1][k] + red[2][k] + red[3][k];
            pooled[bc * 9 + k] = pk * (1.0f / 1024.0f);
            tot += pk;
        }
        float mm = fmaxf(fmaxf(red[0][9], red[1][9]),
                         fmaxf(red[2][9], red[3][9]));
        avg[bc] = tot * (1.0f / (float)HW);
        mx[bc]  = mm;
    }
}

// ---------------------------------------------------------------------------
// Kernel 2: per-batch theta (sigmoid of shared-MLP) and h = relu(bn(proj1(pooled)))
// fc(avg)+fc(mx) = (relu(avg@W1^T)+relu(mx@W1^T)) @ W2^T  (second layer linear)
// ---------------------------------------------------------------------------
__global__ __launch_bounds__(256) void k_theta_hh(
    const float* __restrict__ avg, const float* __restrict__ mx,
    const float* __restrict__ pooled,
    const float* __restrict__ cam_w1, const float* __restrict__ cam_w2,
    const float* __restrict__ proj_w1,
    const float* __restrict__ bn_gamma, const float* __restrict__ bn_beta,
    float* __restrict__ theta, float* __restrict__ hh)
{
    int b = blockIdx.x;
    int t = threadIdx.x;
    __shared__ float s_av[CCH], s_mx[CCH], s_pool[CCH * 9], s_h1p[96], s_h1[RCH];
    if (t < CCH) { s_av[t] = avg[b * CCH + t]; s_mx[t] = mx[b * CCH + t]; }
    for (int i = t; i < CCH * 9; i += 256) s_pool[i] = pooled[b * CCH * 9 + i];
    __syncthreads();
    if (t < 96) {
        int r = t % 48, sel = t / 48;
        const float* src = sel ? s_mx : s_av;
        const float* w = cam_w1 + r * CCH;
        float acc = 0.f;
        for (int c = 0; c < CCH; ++c) acc += src[c] * w[c];
        s_h1p[sel * 48 + r] = fmaxf(acc, 0.f);
    }
    __syncthreads();
    if (t < RCH) s_h1[t] = s_h1p[t] + s_h1p[48 + t];
    __syncthreads();
    if (t < CCH) {
        const float* w = cam_w2 + t * RCH;
        float acc = 0.f;
        for (int r = 0; r < RCH; ++r) acc += s_h1[r] * w[r];
        theta[b * CCH + t] = 1.0f / (1.0f + expf(-acc));
    }
    float bn_s = 1.0f / sqrtf(1.0f + 1e-5f);
    for (int i = t; i < RCH * 9; i += 256) {
        int r = i / 9, k = i % 9;
        const float* w = proj_w1 + r * CCH;
        float acc = 0.f;
        for (int c = 0; c < CCH; ++c) acc += s_pool[c * 9 + k] * w[c];
        float val = acc * (bn_gamma[r] * bn_s) + bn_beta[r];
        hh[b * RCH * 9 + i] = fmaxf(val, 0.f);
    }
}

// ---------------------------------------------------------------------------
// Kernel 3: per-(b,c,k): s_g = <h[b,:,k], proj_w2[g*C+c,:]>, softmax over g,
// weight = sum_g softmax_g * adk[g,c,k]
// ---------------------------------------------------------------------------
__global__ __launch_bounds__(256) void k_weight(
    const float* __restrict__ hh, const float* __restrict__ proj_w2,
    const float* __restrict__ adk, float* __restrict__ wgt)
{
    int gid = blockIdx.x * 256 + threadIdx.x;
    if (gid >= BCTOT * 9) return;
    int b = gid / (CCH * 9);
    int rem = gid % (CCH * 9);
    int c = rem / 9, k = rem % 9;
    const float* hv = hh + b * RCH * 9 + k;
    float sg[4];
#pragma unroll
    for (int g = 0; g < 4; ++g) {
        const float* w = proj_w2 + (size_t)(g * CCH + c) * RCH;
        float acc = 0.f;
        for (int r = 0; r < RCH; ++r) acc += hv[r * 9] * w[r];
        sg[g] = acc;
    }
    float mxv = fmaxf(fmaxf(sg[0], sg[1]), fmaxf(sg[2], sg[3]));
    float e[4];
    float sum = 0.f;
#pragma unroll
    for (int g = 0; g < 4; ++g) { e[g] = expf(sg[g] - mxv); sum += e[g]; }
    float inv = 1.0f / sum;
    float acc = 0.f;
#pragma unroll
    for (int g = 0; g < 4; ++g)
        acc += (e[g] * inv) * adk[(size_t)(g * CCH + c) * 9 + k];
    wgt[gid] = acc;
}

// ---------------------------------------------------------------------------
// Kernel 4: depthwise 3x3 conv (pad 1) with per-plane kernel; theta-center
// adjustment folded in (uniform per block).
// ---------------------------------------------------------------------------
__global__ __launch_bounds__(256) void k_conv(
    const float* __restrict__ x, const float* __restrict__ wgt,
    const float* __restrict__ theta, float* __restrict__ out)
{
    int bc = blockIdx.x;
    float wr[9];
    float wsum = 0.f;
#pragma unroll
    for (int k = 0; k < 9; ++k) { wr[k] = wgt[bc * 9 + k]; wsum += wr[k]; }
    float th = theta[bc];
    wr[4] -= (wsum - th * wr[4]);   // center: w_c - (w_sum - theta*w_c)
    const float* p = x + (size_t)bc * HW;
    float* o = out + (size_t)bc * HW;
    int t = threadIdx.x;
#pragma unroll
    for (int it = 0; it < 9; ++it) {
        int i4 = t + it * 256;          // 0..2303
        int row = i4 / 24, wq = i4 % 24;
        int w0 = wq * 4;
        float rv[3][6];
#pragma unroll
        for (int dr = 0; dr < 3; ++dr) {
            int r = row + dr - 1;
            if (r < 0 || r > 95) {
                rv[dr][0] = rv[dr][1] = rv[dr][2] = 0.f;
                rv[dr][3] = rv[dr][4] = rv[dr][5] = 0.f;
            } else {
                float4 a = ((const float4*)(p + r * 96))[wq];
                rv[dr][0] = (wq > 0)  ? p[r * 96 + w0 - 1] : 0.f;
                rv[dr][1] = a.x; rv[dr][2] = a.y;
                rv[dr][3] = a.z; rv[dr][4] = a.w;
                rv[dr][5] = (wq < 23) ? p[r * 96 + w0 + 4] : 0.f;
            }
        }
        float res[4];
#pragma unroll
        for (int j = 0; j < 4; ++j) {
            float acc = 0.f;
#pragma unroll
            for (int dr = 0; dr < 3; ++dr)
#pragma unroll
                for (int dc = 0; dc < 3; ++dc)
                    acc += wr[dr * 3 + dc] * rv[dr][j + dc];
            res[j] = acc;
        }
        float4 o4; o4.x = res[0]; o4.y = res[1]; o4.z = res[2]; o4.w = res[3];
        ((float4*)o)[i4] = o4;
    }
}

extern "C" void kernel_launch(void* const* d_in, const int* in_sizes, int n_in,
                              void* d_out, int out_size, void* d_ws, size_t ws_size,
                              hipStream_t stream) {
    const float* x        = (const float*)d_in[0];
    const float* cam_w1   = (const float*)d_in[1];
    const float* cam_w2   = (const float*)d_in[2];
    const float* proj_w1  = (const float*)d_in[3];
    const float* bn_gamma = (const float*)d_in[4];
    const float* bn_beta  = (const float*)d_in[5];
    const float* proj_w2  = (const float*)d_in[6];
    const float* adk      = (const float*)d_in[7];
    float* out = (float*)d_out;
    float* ws  = (float*)d_ws;

    float* avg    = ws;            // 3072
    float* mx     = ws + 3072;     // 3072
    float* pooled = ws + 6144;     // 27648
    float* theta  = ws + 33792;    // 3072
    float* hh     = ws + 36864;    // 16*48*9 = 6912
    float* wgt    = ws + 43776;    // 27648

    k_stats   <<<BCTOT, 256, 0, stream>>>(x, avg, mx, pooled);
    k_theta_hh<<<NB,    256, 0, stream>>>(avg, mx, pooled, cam_w1, cam_w2,
                                          proj_w1, bn_gamma, bn_beta, theta, hh);
    k_weight  <<<(BCTOT * 9) / 256, 256, 0, stream>>>(hh, proj_w2, adk, wgt);
    k_conv    <<<BCTOT, 256, 0, stream>>>(x, wgt, theta, out);
}

// Round 2
// 85.462 us; speedup vs baseline: 1.2558x; 1.2558x over previous
//
#include <hip/hip_runtime.h>
#include <math.h>

#define CCH   192
#define RCH   48
#define NB    16
#define HW    9216    // 96*96
#define BCTOT (NB*CCH) // 3072

// ---------------------------------------------------------------------------
// Kernel 1: per-(b,c) plane -> avg, max, 3x3 pooled means
// One block per (b,c). Each pooled 32x32 block = 256 float4 = exactly blockDim.
// ---------------------------------------------------------------------------
__global__ __launch_bounds__(256) void k_stats(const float* __restrict__ x,
                                               float* __restrict__ avg,
                                               float* __restrict__ mx,
                                               float* __restrict__ pooled)
{
    int bc = blockIdx.x;
    const float4* p4 = (const float4*)(x + (size_t)bc * HW);
    int t = threadIdx.x;
    float ps[9];
    float m = -INFINITY;
#pragma unroll
    for (int k = 0; k < 9; ++k) {
        int kr = k / 3, kc = k % 3;
        int row = kr * 32 + (t >> 3);
        int wq  = kc * 8  + (t & 7);
        float4 v = p4[row * 24 + wq];
        ps[k] = v.x + v.y + v.z + v.w;
        m = fmaxf(m, fmaxf(fmaxf(v.x, v.y), fmaxf(v.z, v.w)));
    }
    // wave (64-lane) reduction
#pragma unroll
    for (int off = 32; off > 0; off >>= 1) {
#pragma unroll
        for (int k = 0; k < 9; ++k) ps[k] += __shfl_down(ps[k], off);
        m = fmaxf(m, __shfl_down(m, off));
    }
    __shared__ float red[4][10];
    int wid = t >> 6, lane = t & 63;
    if (lane == 0) {
#pragma unroll
        for (int k = 0; k < 9; ++k) red[wid][k] = ps[k];
        red[wid][9] = m;
    }
    __syncthreads();
    if (t == 0) {
        float tot = 0.f;
#pragma unroll
        for (int k = 0; k < 9; ++k) {
            float pk = red[0][k] + red[1][k] + red[2][k] + red[3][k];
            pooled[bc * 9 + k] = pk * (1.0f / 1024.0f);
            tot += pk;
        }
        float mm = fmaxf(fmaxf(red[0][9], red[1][9]),
                         fmaxf(red[2][9], red[3][9]));
        avg[bc] = tot * (1.0f / (float)HW);
        mx[bc]  = mm;
    }
}

// ---------------------------------------------------------------------------
// Kernel 2: per-batch theta (sigmoid of shared-MLP) and h = relu(bn(proj1(pooled)))
// fc(avg)+fc(mx) = (relu(avg@W1^T)+relu(mx@W1^T)) @ W2^T  (second layer linear)
// ---------------------------------------------------------------------------
__global__ __launch_bounds__(256) void k_theta_hh(
    const float* __restrict__ avg, const float* __restrict__ mx,
    const float* __restrict__ pooled,
    const float* __restrict__ cam_w1, const float* __restrict__ cam_w2,
    const float* __restrict__ proj_w1,
    const float* __restrict__ bn_gamma, const float* __restrict__ bn_beta,
    float* __restrict__ theta, float* __restrict__ hh)
{
    int b = blockIdx.x;
    int t = threadIdx.x;
    __shared__ float s_av[CCH], s_mx[CCH], s_pool[CCH * 9], s_h1p[96], s_h1[RCH];
    if (t < CCH) { s_av[t] = avg[b * CCH + t]; s_mx[t] = mx[b * CCH + t]; }
    for (int i = t; i < CCH * 9; i += 256) s_pool[i] = pooled[b * CCH * 9 + i];
    __syncthreads();
    if (t < 96) {
        int r = t % 48, sel = t / 48;
        const float* src = sel ? s_mx : s_av;
        const float* w = cam_w1 + r * CCH;
        float acc = 0.f;
        for (int c = 0; c < CCH; ++c) acc += src[c] * w[c];
        s_h1p[sel * 48 + r] = fmaxf(acc, 0.f);
    }
    __syncthreads();
    if (t < RCH) s_h1[t] = s_h1p[t] + s_h1p[48 + t];
    __syncthreads();
    if (t < CCH) {
        const float* w = cam_w2 + t * RCH;
        float acc = 0.f;
        for (int r = 0; r < RCH; ++r) acc += s_h1[r] * w[r];
        theta[b * CCH + t] = 1.0f / (1.0f + expf(-acc));
    }
    float bn_s = 1.0f / sqrtf(1.0f + 1e-5f);
    for (int i = t; i < RCH * 9; i += 256) {
        int r = i / 9, k = i % 9;
        const float* w = proj_w1 + r * CCH;
        float acc = 0.f;
        for (int c = 0; c < CCH; ++c) acc += s_pool[c * 9 + k] * w[c];
        float val = acc * (bn_gamma[r] * bn_s) + bn_beta[r];
        hh[b * RCH * 9 + i] = fmaxf(val, 0.f);
    }
}

// ---------------------------------------------------------------------------
// Kernel 3: per-(b,c,k): s_g = <h[b,:,k], proj_w2[g*C+c,:]>, softmax over g,
// weight = sum_g softmax_g * adk[g,c,k]
// ---------------------------------------------------------------------------
__global__ __launch_bounds__(256) void k_weight(
    const float* __restrict__ hh, const float* __restrict__ proj_w2,
    const float* __restrict__ adk, float* __restrict__ wgt)
{
    int gid = blockIdx.x * 256 + threadIdx.x;
    if (gid >= BCTOT * 9) return;
    int b = gid / (CCH * 9);
    int rem = gid % (CCH * 9);
    int c = rem / 9, k = rem % 9;
    const float* hv = hh + b * RCH * 9 + k;
    float sg[4];
#pragma unroll
    for (int g = 0; g < 4; ++g) {
        const float* w = proj_w2 + (size_t)(g * CCH + c) * RCH;
        float acc = 0.f;
        for (int r = 0; r < RCH; ++r) acc += hv[r * 9] * w[r];
        sg[g] = acc;
    }
    float mxv = fmaxf(fmaxf(sg[0], sg[1]), fmaxf(sg[2], sg[3]));
    float e[4];
    float sum = 0.f;
#pragma unroll
    for (int g = 0; g < 4; ++g) { e[g] = expf(sg[g] - mxv); sum += e[g]; }
    float inv = 1.0f / sum;
    float acc = 0.f;
#pragma unroll
    for (int g = 0; g < 4; ++g)
        acc += (e[g] * inv) * adk[(size_t)(g * CCH + c) * 9 + k];
    wgt[gid] = acc;
}

// ---------------------------------------------------------------------------
// Kernel 4: depthwise 3x3 conv (pad 1), vertical sliding window.
// Each thread: 4-wide x 12-row output strip; walks 14 input rows once,
// 3 rotating accumulators (all indices compile-time via full unroll).
// ---------------------------------------------------------------------------
__global__ __launch_bounds__(256) void k_conv(
    const float* __restrict__ x, const float* __restrict__ wgt,
    const float* __restrict__ theta, float* __restrict__ out)
{
    int gid = blockIdx.x * 256 + threadIdx.x;
    int plane = gid / 192;          // 192 = 8 rowgroups * 24 wq
    int sub   = gid % 192;
    int rg = sub / 24, wq = sub % 24;
    int r0 = rg * 12;
    int w0 = wq * 4;

    float wr[9];
    float wsum = 0.f;
#pragma unroll
    for (int k = 0; k < 9; ++k) { wr[k] = wgt[plane * 9 + k]; wsum += wr[k]; }
    float th = theta[plane];
    wr[4] = wr[4] * (1.f + th) - wsum;   // fold theta-center adjustment

    const float* p = x + (size_t)plane * HW;
    float* o = out + (size_t)plane * HW;

    float acc[3][4];
#pragma unroll
    for (int i = 0; i <= 13; ++i) {
        int r = r0 - 1 + i;
        float win[6];
        bool inr = (r >= 0) && (r < 96);
        const float* prow = p + r * 96;
        if (inr) {
            float4 a = ((const float4*)prow)[wq];
            win[0] = (wq > 0)  ? prow[w0 - 1] : 0.f;
            win[1] = a.x; win[2] = a.y; win[3] = a.z; win[4] = a.w;
            win[5] = (wq < 23) ? prow[w0 + 4] : 0.f;
        } else {
#pragma unroll
            for (int j = 0; j < 6; ++j) win[j] = 0.f;
        }
        // input row r is top-tap (kernel row 0) for output o=r+1
        if (i <= 11) {
#pragma unroll
            for (int j = 0; j < 4; ++j)
                acc[i % 3][j] = wr[0] * win[j] + wr[1] * win[j + 1] + wr[2] * win[j + 2];
        }
        // mid-tap (kernel row 1) for output o=r
        if (i >= 1 && i <= 12) {
#pragma unroll
            for (int j = 0; j < 4; ++j)
                acc[(i - 1) % 3][j] += wr[3] * win[j] + wr[4] * win[j + 1] + wr[5] * win[j + 2];
        }
        // bottom-tap (kernel row 2) for output o=r-1 -> complete, store
        if (i >= 2) {
            const int s = (i - 2) % 3;
#pragma unroll
            for (int j = 0; j < 4; ++j)
                acc[s][j] += wr[6] * win[j] + wr[7] * win[j + 1] + wr[8] * win[j + 2];
            float4 o4;
            o4.x = acc[s][0]; o4.y = acc[s][1]; o4.z = acc[s][2]; o4.w = acc[s][3];
            ((float4*)(o + (size_t)(r - 1) * 96))[wq] = o4;
        }
    }
}

extern "C" void kernel_launch(void* const* d_in, const int* in_sizes, int n_in,
                              void* d_out, int out_size, void* d_ws, size_t ws_size,
                              hipStream_t stream) {
    const float* x        = (const float*)d_in[0];
    const float* cam_w1   = (const float*)d_in[1];
    const float* cam_w2   = (const float*)d_in[2];
    const float* proj_w1  = (const float*)d_in[3];
    const float* bn_gamma = (const float*)d_in[4];
    const float* bn_beta  = (const float*)d_in[5];
    const float* proj_w2  = (const float*)d_in[6];
    const float* adk      = (const float*)d_in[7];
    float* out = (float*)d_out;
    float* ws  = (float*)d_ws;

    float* avg    = ws;            // 3072
    float* mx     = ws + 3072;     // 3072
    float* pooled = ws + 6144;     // 27648
    float* theta  = ws + 33792;    // 3072
    float* hh     = ws + 36864;    // 16*48*9 = 6912
    float* wgt    = ws + 43776;    // 27648

    k_stats   <<<BCTOT, 256, 0, stream>>>(x, avg, mx, pooled);
    k_theta_hh<<<NB,    256, 0, stream>>>(avg, mx, pooled, cam_w1, cam_w2,
                                          proj_w1, bn_gamma, bn_beta, theta, hh);
    k_weight  <<<(BCTOT * 9) / 256, 256, 0, stream>>>(hh, proj_w2, adk, wgt);
    k_conv    <<<(BCTOT * 192) / 256, 256, 0, stream>>>(x, wgt, theta, out);
}